// Round 13
// baseline (13051.344 us; speedup 1.0000x reference)
//
#include <hip/hip_runtime.h>
#include <math.h>

typedef __attribute__((ext_vector_type(8))) short bf16x8;   // 8 bf16 (4 VGPR)
typedef __attribute__((ext_vector_type(4))) float f32x4;    // MFMA C/D

static constexpr int Tt = 1024;
static constexpr int Hh = 512;
static constexpr int Cc = 10;

static constexpr int NXCD = 8;       // XCDs; each runs an independent group
static constexpr int BPX  = 32;      // blocks (CUs) per XCD
static constexpr int UPB  = 16;      // hidden units per block (64 gate rows)
static constexpr int NB   = 16;      // batch rows per XCD (8*16 = 128)
static constexpr int THREADS = 320;  // 4 GEMM waves (one gate each) + 1 owner wave
static constexpr int GRID = 256;     // 1 block per CU (LDS pad forces it)

// ws bytes: [0,1024) flags[8][32] | [1024,2048) rank counters | pad
//           [4096, +256KB) h_hi[2][8][16][512] bf16 | then h_lo 256KB
static constexpr size_t WS_HHI_B = 4096;
static constexpr size_t WS_HLO_B = 4096 + 262144;

__device__ __forceinline__ unsigned short f2bf(float f) {
    unsigned u = __builtin_bit_cast(unsigned, f);
    return (unsigned short)((u + 0x7FFFu + ((u >> 16) & 1u)) >> 16);   // RNE
}
__device__ __forceinline__ float bf2f(unsigned short h) {
    unsigned u = ((unsigned)h) << 16;
    return __builtin_bit_cast(float, u);
}
__device__ __forceinline__ float dot4(float4 a, float4 b) {
    return a.x * b.x + a.y * b.y + a.z * b.z + a.w * b.w;
}
__device__ __forceinline__ float fsig(float x) {
    const float e = __builtin_amdgcn_exp2f(x * -1.44269504f);
    return __builtin_amdgcn_rcpf(1.0f + e);
}
__device__ __forceinline__ float ftanh(float x) {
    const float e = __builtin_amdgcn_exp2f(x * -2.88539008f);
    return 2.0f * __builtin_amdgcn_rcpf(1.0f + e) - 1.0f;
}

__global__ __launch_bounds__(THREADS, 2)
void lstm_fused(const float* __restrict__ x,
                const float* __restrict__ w_ih,
                const float* __restrict__ w_hh,
                const float* __restrict__ b_ih,
                const float* __restrict__ b_hh,
                const float* __restrict__ w_t,
                const float* __restrict__ w_fc,
                const float* __restrict__ b_fc,
                float* __restrict__ out,
                float* __restrict__ ws)
{
    const int tid  = threadIdx.x;
    const int lane = tid & 63;
    const int wv   = tid >> 6;          // 0..3 = gate waves, 4 = owner wave
    const int frow = lane & 15;         // A row / B batch col
    const int kgrp = lane >> 4;         // 8-elem K group within a 32-K step

    int* flags    = (int*)ws;                 // [xcd*32 + rank]
    int* counters = (int*)ws + 256;           // init-time rank claim
    unsigned short* hg_hi = (unsigned short*)((char*)ws + WS_HHI_B);
    unsigned short* hg_lo = (unsigned short*)((char*)ws + WS_HLO_B);

    // LDS: gbuf 5 KB (+80 KB pad: forces 1 block/CU for the rank census)
    __shared__ __align__(16) float gbuf[64 * 20];     // [gaterow][batch]
    __shared__ int lds_pad[20480];                    // 80 KB; xchg lives here
    int* xchg = lds_pad;

    // ---- discover physical XCD, claim a rank ----
    if (tid == 0) {
        int xr;
        asm volatile("s_getreg_b32 %0, hwreg(20, 0, 32)" : "=s"(xr));
        const int xcd = xr & 7;
        xchg[0] = xcd;
        xchg[1] = atomicAdd(&counters[xcd * 32], 1) & 31;
    }
    __syncthreads();
    const int xcd  = xchg[0];
    const int rank = xchg[1];
    __syncthreads();
    const int fbase = xcd * BPX;

    // ---- W fragments into registers: gate wv, 16 kk x (hi,lo) = 128 VGPR ----
    bf16x8 wahi[16], walo[16];
    if (wv < 4) {
        const float* wr = w_hh + (size_t)(wv * Hh + rank * UPB + frow) * Hh;
        #pragma unroll
        for (int kk = 0; kk < 16; ++kk) {
            const float4* s = (const float4*)(wr + kk * 32 + kgrp * 8);
            const float4 f0 = s[0], f1 = s[1];
            const float f[8] = { f0.x, f0.y, f0.z, f0.w, f1.x, f1.y, f1.z, f1.w };
            bf16x8 vhi, vlo;
            #pragma unroll
            for (int j = 0; j < 8; ++j) {
                const unsigned short hb = f2bf(f[j]);
                vhi[j] = (short)hb;
                vlo[j] = (short)f2bf(f[j] - bf2f(hb));
            }
            wahi[kk] = vhi;
            walo[kk] = vlo;
        }
    }

    // ---- elementwise role (tid < 256): thread -> (u, b) ----
    const int u  = tid & 15;
    const int b_ = (tid >> 4) & 15;
    const int gj = rank * UPB + u;
    const int gb = xcd * NB + b_;
    float wih_r[4], bias_r[4];
    #pragma unroll
    for (int g = 0; g < 4; ++g) {
        wih_r[g]  = w_ih[g * Hh + gj];
        bias_r[g] = b_ih[g * Hh + gj] + b_hh[g * Hh + gj];
    }
    float creg = 0.0f;

    // ---- owner role (wave 4, ranks 0..15): one batch row's output chain ----
    const bool owner = (rank < NB);
    const int  gb_own = xcd * NB + rank;
    float S1w[Cc], S2w[Cc], bfc_r[Cc];
    #pragma unroll
    for (int c = 0; c < Cc; ++c) { S1w[c] = 0.f; S2w[c] = 0.f; bfc_r[c] = b_fc[c]; }

    for (int t = 0; t <= Tt; ++t) {
        const int rb = t & 1, wb = rb ^ 1;   // rb buffer holds h^(t-1)
        const unsigned short* hbase_hi = hg_hi + (size_t)(rb * NXCD + xcd) * NB * Hh;
        const unsigned short* hbase_lo = hg_lo + (size_t)(rb * NXCD + xcd) * NB * Hh;

        if (wv == 4) {
            // ---- owner: emit out(t-1) from h^(t-1), concurrent with GEMM ----
            if (t > 0 && owner) {
                const size_t rbase = (size_t)rank * Hh + lane * 8;
                const bf16x8 vh = *(const bf16x8*)(hbase_hi + rbase);
                const bf16x8 vl = *(const bf16x8*)(hbase_lo + rbase);
                float f[8];
                #pragma unroll
                for (int j = 0; j < 8; ++j)
                    f[j] = bf2f((unsigned short)vh[j]) + bf2f((unsigned short)vl[j]);
                const float4 hA = make_float4(f[0], f[1], f[2], f[3]);
                const float4 hB = make_float4(f[4], f[5], f[6], f[7]);
                const float4* wt4 = (const float4*)w_t;
                const float4* wf4 = (const float4*)w_fc;
                float r[12];
                r[0] = dot4(hA, wt4[lane * 2])       + dot4(hB, wt4[lane * 2 + 1]);
                r[1] = dot4(hA, wt4[128 + lane * 2]) + dot4(hB, wt4[128 + lane * 2 + 1]);
                #pragma unroll
                for (int c = 0; c < Cc; ++c)
                    r[2 + c] = dot4(hA, wf4[c * 128 + lane * 2])
                             + dot4(hB, wf4[c * 128 + lane * 2 + 1]);
                #pragma unroll
                for (int m = 1; m <= 32; m <<= 1)
                    #pragma unroll
                    for (int k2 = 0; k2 < 12; ++k2)
                        r[k2] += __shfl_xor(r[k2], m, 64);

                if (lane == 0) {
                    const float a = r[0], b2 = r[1];
                    float* po = out + ((size_t)gb_own * Tt + (t - 1)) * Cc;
                    #pragma unroll
                    for (int c = 0; c < Cc; ++c) {
                        const float hw = r[2 + c];
                        po[c] = hw + a * S1w[c] + S2w[c] + bfc_r[c];
                        S1w[c] += hw;
                        S2w[c] += b2 * hw;
                    }
                }
            }
        } else {
            // ---- GEMM: gate wv, B fragments direct from global (XCD L2) ----
            f32x4 a0 = { 0.f, 0.f, 0.f, 0.f };
            f32x4 a1 = { 0.f, 0.f, 0.f, 0.f };
            f32x4 a2 = { 0.f, 0.f, 0.f, 0.f };
            if (t > 0 && t < Tt) {
                const unsigned short* ph = hbase_hi + (size_t)frow * Hh + kgrp * 8;
                const unsigned short* pl = hbase_lo + (size_t)frow * Hh + kgrp * 8;
                #pragma unroll 4
                for (int kk = 0; kk < 16; ++kk) {
                    const bf16x8 bhi = *(const bf16x8*)(ph + kk * 32);
                    const bf16x8 blo = *(const bf16x8*)(pl + kk * 32);
                    a0 = __builtin_amdgcn_mfma_f32_16x16x32_bf16(wahi[kk], bhi, a0, 0, 0, 0);
                    a1 = __builtin_amdgcn_mfma_f32_16x16x32_bf16(wahi[kk], blo, a1, 0, 0, 0);
                    a2 = __builtin_amdgcn_mfma_f32_16x16x32_bf16(walo[kk], bhi, a2, 0, 0, 0);
                }
            }
            if (t < Tt) {
                // C layout: col(lane&15)=batch, row=(lane>>4)*4+reg = unit
                #pragma unroll
                for (int r = 0; r < 4; ++r)
                    gbuf[(wv * 16 + kgrp * 4 + r) * 20 + frow] = a0[r] + a1[r] + a2[r];
            }
        }
        if (t == Tt) break;

        float xv = 0.f;
        if (tid < 256) xv = x[(size_t)gb * Tt + t];
        __syncthreads();                 // gbuf ready for phase C

        // ---- C: LSTM elementwise, write h^(t) hi/lo (plain -> XCD L2) ----
        if (tid < 256) {
            const float gi = gbuf[(0 * 16 + u) * 20 + b_] + xv * wih_r[0] + bias_r[0];
            const float gf = gbuf[(1 * 16 + u) * 20 + b_] + xv * wih_r[1] + bias_r[1];
            const float gg = gbuf[(2 * 16 + u) * 20 + b_] + xv * wih_r[2] + bias_r[2];
            const float go = gbuf[(3 * 16 + u) * 20 + b_] + xv * wih_r[3] + bias_r[3];
            creg = fsig(gf) * creg + fsig(gi) * ftanh(gg);
            const float hnew = fsig(go) * ftanh(creg);
            const unsigned short hb2 = f2bf(hnew);
            const unsigned short lb2 = f2bf(hnew - bf2f(hb2));
            const size_t hoff = ((size_t)(wb * NXCD + xcd) * NB + b_) * Hh + gj;
            hg_hi[hoff] = hb2;
            hg_lo[hoff] = lb2;
        }
        __syncthreads();   // vmcnt(0) drained: h^(t) visible in XCD L2

        // ---- D: plain-store flag (ordered after the drain) ----
        if (tid == 0)
            *(volatile int*)(flags + fbase + rank) = t + 1;

        // ---- E: lanes 0-31 poll flags; buffer_inv per round (PROVEN form) ----
        if (tid < 32) {
            const volatile int* fl = (const volatile int*)(flags + fbase + tid);
            int v = *fl;
            while (__any(v < t + 1)) {
                __builtin_amdgcn_s_sleep(1);
                asm volatile("buffer_inv\n\ts_waitcnt vmcnt(0)" ::: "memory");
                v = *fl;
            }
            // final L1 invalidate: peers' h (in shared XCD L2) becomes visible
            asm volatile("buffer_inv\n\ts_waitcnt vmcnt(0)" ::: "memory");
        }
        __syncthreads();   // block released with clean L1
    }
}

extern "C" void kernel_launch(void* const* d_in, const int* in_sizes, int n_in,
                              void* d_out, int out_size, void* d_ws, size_t ws_size,
                              hipStream_t stream)
{
    const float* xp  = (const float*)d_in[0];
    const float* wih = (const float*)d_in[1];
    const float* whh = (const float*)d_in[2];
    const float* bih = (const float*)d_in[3];
    const float* bhh = (const float*)d_in[4];
    const float* wt  = (const float*)d_in[5];
    const float* wfc = (const float*)d_in[6];
    const float* bfc = (const float*)d_in[7];
    float* outp = (float*)d_out;
    float* ws   = (float*)d_ws;

    // zero flags + rank counters each call (graph-capturable)
    (void)hipMemsetAsync(d_ws, 0, 4096, stream);

    hipLaunchKernelGGL(lstm_fused, dim3(GRID), dim3(THREADS), 0, stream,
                       xp, wih, whh, bih, bhh, wt, wfc, bfc, outp, ws);
}

// Round 14
// 7065.897 us; speedup vs baseline: 1.8471x; 1.8471x over previous
//
#include <hip/hip_runtime.h>
#include <math.h>

typedef __attribute__((ext_vector_type(8))) short bf16x8;   // 8 bf16 (4 VGPR)
typedef __attribute__((ext_vector_type(4))) float f32x4;    // MFMA C/D

static constexpr int Tt = 1024;
static constexpr int Hh = 512;
static constexpr int Cc = 10;

static constexpr int NXCD = 8;       // XCDs; each runs an independent group
static constexpr int BPX  = 32;      // blocks (CUs) per XCD
static constexpr int UPB  = 16;      // hidden units per block (64 gate rows)
static constexpr int NB   = 16;      // batch rows per XCD (8*16 = 128)
static constexpr int THREADS = 320;  // 4 GEMM waves (one gate each) + 1 owner wave
static constexpr int GRID = 256;     // 1 block per CU (85 KB LDS forces it)

// ws bytes: [0,1024) flags[8][32] | [1024,2048) rank counters | pad
//           [4096, +256KB) h_hi[2][8][16][512] bf16 | then h_lo 256KB
static constexpr size_t WS_HHI_B = 4096;
static constexpr size_t WS_HLO_B = 4096 + 262144;

__device__ __forceinline__ unsigned short f2bf(float f) {
    unsigned u = __builtin_bit_cast(unsigned, f);
    return (unsigned short)((u + 0x7FFFu + ((u >> 16) & 1u)) >> 16);   // RNE
}
__device__ __forceinline__ float bf2f(unsigned short h) {
    unsigned u = ((unsigned)h) << 16;
    return __builtin_bit_cast(float, u);
}
__device__ __forceinline__ float dot4(float4 a, float4 b) {
    return a.x * b.x + a.y * b.y + a.z * b.z + a.w * b.w;
}
__device__ __forceinline__ float fsig(float x) {
    const float e = __builtin_amdgcn_exp2f(x * -1.44269504f);
    return __builtin_amdgcn_rcpf(1.0f + e);
}
__device__ __forceinline__ float ftanh(float x) {
    const float e = __builtin_amdgcn_exp2f(x * -2.88539008f);
    return 2.0f * __builtin_amdgcn_rcpf(1.0f + e) - 1.0f;
}

__global__ __launch_bounds__(THREADS, 2)
void lstm_fused(const float* __restrict__ x,
                const float* __restrict__ w_ih,
                const float* __restrict__ w_hh,
                const float* __restrict__ b_ih,
                const float* __restrict__ b_hh,
                const float* __restrict__ w_t,
                const float* __restrict__ w_fc,
                const float* __restrict__ b_fc,
                float* __restrict__ out,
                float* __restrict__ ws)
{
    const int tid  = threadIdx.x;
    const int lane = tid & 63;
    const int wv   = tid >> 6;          // 0..3 = gate waves, 4 = owner wave
    const int frow = lane & 15;         // A row / B batch col
    const int kgrp = lane >> 4;         // 8-elem K group within a 32-K step

    int* flags    = (int*)ws;                 // [xcd*32 + rank]
    int* counters = (int*)ws + 256;           // init-time rank claim
    unsigned short* hg_hi = (unsigned short*)((char*)ws + WS_HHI_B);
    unsigned short* hg_lo = (unsigned short*)((char*)ws + WS_HLO_B);

    // LDS: gbuf 5 KB + REAL 80 KB pad (volatile-touched) = 85 KB -> 1 block/CU
    __shared__ __align__(16) float gbuf[64 * 20];     // [gaterow][batch]
    __shared__ int lds_pad[20480];                    // 80 KB
    int* xchg = lds_pad;

    // volatile store at runtime offset: pad cannot be DCE'd or shrunk
    ((volatile char*)lds_pad)[(size_t)tid * 255] = 0;

    // ---- discover physical XCD, claim a rank ----
    if (tid == 0) {
        int xr;
        asm volatile("s_getreg_b32 %0, hwreg(20, 0, 32)" : "=s"(xr));
        const int xcd = xr & 7;
        xchg[0] = xcd;
        xchg[1] = atomicAdd(&counters[xcd * 32], 1) & 31;
    }
    __syncthreads();
    const int xcd  = xchg[0];
    const int rank = xchg[1];
    __syncthreads();
    const int fbase = xcd * BPX;

    // ---- W fragments into registers: gate wv, 16 kk x (hi,lo) = 128 VGPR ----
    bf16x8 wahi[16], walo[16];
    if (wv < 4) {
        const float* wr = w_hh + (size_t)(wv * Hh + rank * UPB + frow) * Hh;
        #pragma unroll
        for (int kk = 0; kk < 16; ++kk) {
            const float4* s = (const float4*)(wr + kk * 32 + kgrp * 8);
            const float4 f0 = s[0], f1 = s[1];
            const float f[8] = { f0.x, f0.y, f0.z, f0.w, f1.x, f1.y, f1.z, f1.w };
            bf16x8 vhi, vlo;
            #pragma unroll
            for (int j = 0; j < 8; ++j) {
                const unsigned short hb = f2bf(f[j]);
                vhi[j] = (short)hb;
                vlo[j] = (short)f2bf(f[j] - bf2f(hb));
            }
            // pin: origin becomes opaque -> compiler cannot sink/remat the load
            asm("" : "+v"(vhi), "+v"(vlo));
            wahi[kk] = vhi;
            walo[kk] = vlo;
        }
    }

    // ---- elementwise role (tid < 256): thread -> (u, b) ----
    const int u  = tid & 15;
    const int b_ = (tid >> 4) & 15;
    const int gj = rank * UPB + u;
    const int gb = xcd * NB + b_;
    float wih_r[4], bias_r[4];
    #pragma unroll
    for (int g = 0; g < 4; ++g) {
        wih_r[g]  = w_ih[g * Hh + gj];
        bias_r[g] = b_ih[g * Hh + gj] + b_hh[g * Hh + gj];
    }
    float creg = 0.0f;

    // ---- owner role (wave 4, ranks 0..15): one batch row's output chain ----
    const bool owner = (rank < NB);
    const int  gb_own = xcd * NB + rank;
    float S1w[Cc], S2w[Cc], bfc_r[Cc];
    #pragma unroll
    for (int c = 0; c < Cc; ++c) { S1w[c] = 0.f; S2w[c] = 0.f; bfc_r[c] = b_fc[c]; }

    for (int t = 0; t <= Tt; ++t) {
        const int rb = t & 1, wb = rb ^ 1;   // rb buffer holds h^(t-1)
        const unsigned short* hbase_hi = hg_hi + (size_t)(rb * NXCD + xcd) * NB * Hh;
        const unsigned short* hbase_lo = hg_lo + (size_t)(rb * NXCD + xcd) * NB * Hh;

        if (wv == 4) {
            // ---- owner: emit out(t-1) from h^(t-1), concurrent with GEMM ----
            if (t > 0 && owner) {
                const size_t rbase = (size_t)rank * Hh + lane * 8;
                const bf16x8 vh = *(const bf16x8*)(hbase_hi + rbase);
                const bf16x8 vl = *(const bf16x8*)(hbase_lo + rbase);
                float f[8];
                #pragma unroll
                for (int j = 0; j < 8; ++j)
                    f[j] = bf2f((unsigned short)vh[j]) + bf2f((unsigned short)vl[j]);
                const float4 hA = make_float4(f[0], f[1], f[2], f[3]);
                const float4 hB = make_float4(f[4], f[5], f[6], f[7]);
                const float4* wt4 = (const float4*)w_t;
                const float4* wf4 = (const float4*)w_fc;
                float r[12];
                r[0] = dot4(hA, wt4[lane * 2])       + dot4(hB, wt4[lane * 2 + 1]);
                r[1] = dot4(hA, wt4[128 + lane * 2]) + dot4(hB, wt4[128 + lane * 2 + 1]);
                #pragma unroll
                for (int c = 0; c < Cc; ++c)
                    r[2 + c] = dot4(hA, wf4[c * 128 + lane * 2])
                             + dot4(hB, wf4[c * 128 + lane * 2 + 1]);
                #pragma unroll
                for (int m = 1; m <= 32; m <<= 1)
                    #pragma unroll
                    for (int k2 = 0; k2 < 12; ++k2)
                        r[k2] += __shfl_xor(r[k2], m, 64);

                if (lane == 0) {
                    const float a = r[0], b2 = r[1];
                    float* po = out + ((size_t)gb_own * Tt + (t - 1)) * Cc;
                    #pragma unroll
                    for (int c = 0; c < Cc; ++c) {
                        const float hw = r[2 + c];
                        po[c] = hw + a * S1w[c] + S2w[c] + bfc_r[c];
                        S1w[c] += hw;
                        S2w[c] += b2 * hw;
                    }
                }
            }
        } else {
            // ---- GEMM: gate wv, B fragments direct from global (XCD L2) ----
            f32x4 a0 = { 0.f, 0.f, 0.f, 0.f };
            f32x4 a1 = { 0.f, 0.f, 0.f, 0.f };
            f32x4 a2 = { 0.f, 0.f, 0.f, 0.f };
            if (t > 0 && t < Tt) {
                const unsigned short* ph = hbase_hi + (size_t)frow * Hh + kgrp * 8;
                const unsigned short* pl = hbase_lo + (size_t)frow * Hh + kgrp * 8;
                #pragma unroll
                for (int kk = 0; kk < 16; ++kk) {
                    const bf16x8 bhi = *(const bf16x8*)(ph + kk * 32);
                    const bf16x8 blo = *(const bf16x8*)(pl + kk * 32);
                    a0 = __builtin_amdgcn_mfma_f32_16x16x32_bf16(wahi[kk], bhi, a0, 0, 0, 0);
                    a1 = __builtin_amdgcn_mfma_f32_16x16x32_bf16(wahi[kk], blo, a1, 0, 0, 0);
                    a2 = __builtin_amdgcn_mfma_f32_16x16x32_bf16(walo[kk], bhi, a2, 0, 0, 0);
                }
            }
            if (t < Tt) {
                // C layout: col(lane&15)=batch, row=(lane>>4)*4+reg = unit
                #pragma unroll
                for (int r = 0; r < 4; ++r)
                    gbuf[(wv * 16 + kgrp * 4 + r) * 20 + frow] = a0[r] + a1[r] + a2[r];
            }
        }
        if (t == Tt) break;

        float xv = 0.f;
        if (tid < 256) xv = x[(size_t)gb * Tt + t];
        __syncthreads();                 // gbuf ready for phase C

        // ---- C: LSTM elementwise, write h^(t) hi/lo (plain -> XCD L2) ----
        if (tid < 256) {
            const float gi = gbuf[(0 * 16 + u) * 20 + b_] + xv * wih_r[0] + bias_r[0];
            const float gf = gbuf[(1 * 16 + u) * 20 + b_] + xv * wih_r[1] + bias_r[1];
            const float gg = gbuf[(2 * 16 + u) * 20 + b_] + xv * wih_r[2] + bias_r[2];
            const float go = gbuf[(3 * 16 + u) * 20 + b_] + xv * wih_r[3] + bias_r[3];
            creg = fsig(gf) * creg + fsig(gi) * ftanh(gg);
            const float hnew = fsig(go) * ftanh(creg);
            const unsigned short hb2 = f2bf(hnew);
            const unsigned short lb2 = f2bf(hnew - bf2f(hb2));
            const size_t hoff = ((size_t)(wb * NXCD + xcd) * NB + b_) * Hh + gj;
            hg_hi[hoff] = hb2;
            hg_lo[hoff] = lb2;
        }
        __syncthreads();   // vmcnt(0) drained: h^(t) visible in XCD L2

        // ---- D: plain-store flag (ordered after the drain) ----
        if (tid == 0)
            *(volatile int*)(flags + fbase + rank) = t + 1;

        // ---- E: lanes 0-31 poll flags; buffer_inv per round (PROVEN form) ----
        if (tid < 32) {
            const volatile int* fl = (const volatile int*)(flags + fbase + tid);
            int v = *fl;
            while (__any(v < t + 1)) {
                __builtin_amdgcn_s_sleep(1);
                asm volatile("buffer_inv\n\ts_waitcnt vmcnt(0)" ::: "memory");
                v = *fl;
            }
            // final L1 invalidate: peers' h (in shared XCD L2) becomes visible
            asm volatile("buffer_inv\n\ts_waitcnt vmcnt(0)" ::: "memory");
        }
        __syncthreads();   // block released with clean L1
    }
}

extern "C" void kernel_launch(void* const* d_in, const int* in_sizes, int n_in,
                              void* d_out, int out_size, void* d_ws, size_t ws_size,
                              hipStream_t stream)
{
    const float* xp  = (const float*)d_in[0];
    const float* wih = (const float*)d_in[1];
    const float* whh = (const float*)d_in[2];
    const float* bih = (const float*)d_in[3];
    const float* bhh = (const float*)d_in[4];
    const float* wt  = (const float*)d_in[5];
    const float* wfc = (const float*)d_in[6];
    const float* bfc = (const float*)d_in[7];
    float* outp = (float*)d_out;
    float* ws   = (float*)d_ws;

    // zero flags + rank counters each call (graph-capturable)
    (void)hipMemsetAsync(d_ws, 0, 4096, stream);

    hipLaunchKernelGGL(lstm_fused, dim3(GRID), dim3(THREADS), 0, stream,
                       xp, wih, whh, bih, bhh, wt, wfc, bfc, outp, ws);
}